// Round 16
// baseline (174.957 us; speedup 1.0000x reference)
//
#include <hip/hip_runtime.h>
#include <math.h>

// Problem constants (fixed by the reference)
constexpr int kB    = 4;
constexpr int kN    = 3136;
constexpr int kN0   = 12544;
constexpr int kH    = 112, kW = 112;
constexpr int kHW   = kH * kW;          // 12544
constexpr int kCIN  = 128;
constexpr int kCHID = 512;
constexpr int kCOUT = 128;
constexpr int kROWS = kB * kN;          // 12544
constexpr int kPTS  = kB * kN0;         // 50176
constexpr int kBHW  = kB * kHW;         // 50176
constexpr int kSEG  = kBHW + kROWS;     // 62720 combined CSR segments
constexpr int kScanBlks = (kSEG + 255) / 256;   // 245
constexpr int kDwBlks   = kB * kHW / 16;        // 3136 (multiple of 8)
constexpr float kEPS  = 1e-6f;
constexpr float kBEPS = 1e-5f;

typedef __attribute__((ext_vector_type(8))) short short8;
typedef __attribute__((ext_vector_type(4))) float f32x4;

__device__ __forceinline__ float gelu_f(float x) {
    return 0.5f * x * (1.0f + erff(x * 0.70710678118654752440f));
}
__device__ __forceinline__ float bf2f(short s) {
    union { unsigned u; float f; } v; v.u = ((unsigned)(unsigned short)s) << 16; return v.f;
}
__device__ __forceinline__ short f2bf(float f) {
    union { float f; unsigned u; } v; v.f = f;
    const unsigned r = v.u + 0x7fffu + ((v.u >> 16) & 1u);   // RNE
    return (short)(r >> 16);
}

// ---------------------------------------------------------------------------
// MFMA bf16 GEMM, K-BLOCK operand layout:  T[(k/8)*dim + idx][8].
// (R14 lesson: row-major fragment loads are address-divergent; k-block makes
//  16 lanes contiguous -> 44us/1.3% MfmaUtil fixed to <12us.)
// Fused per-column stats (196 writers/addr = fine; R7: never 3136 writers).
// ---------------------------------------------------------------------------
template <int OUT16, int STATS>
__global__ __launch_bounds__(256) void gemm_kb_k(
    const short* __restrict__ A, const short* __restrict__ W,
    const float* __restrict__ bias, void* __restrict__ Cv,
    float* __restrict__ gsum, float* __restrict__ gsq,
    int M, int N, int K)
{
    __shared__ float ls[64], lq[64];
    if (STATS) {
        if (threadIdx.x < 64) { ls[threadIdx.x] = 0.f; lq[threadIdx.x] = 0.f; }
        __syncthreads();
    }
    const int wave = threadIdx.x >> 6;
    const int lane = threadIdx.x & 63;
    const int r = lane & 15, kg = lane >> 4;
    const int bm = blockIdx.x * 64 + wave * 16;
    const int bn = blockIdx.y * 64;
    f32x4 acc[4];
#pragma unroll
    for (int j = 0; j < 4; ++j) {
        const float bz = bias[bn + j * 16 + r];
        acc[j][0] = bz; acc[j][1] = bz; acc[j][2] = bz; acc[j][3] = bz;
    }
    for (int k0 = 0; k0 < K; k0 += 32) {
        const int kb = (k0 >> 3) + kg;
        const short8 av = *(const short8*)(A + ((size_t)kb * M + bm + r) * 8);
#pragma unroll
        for (int j = 0; j < 4; ++j) {
            const short8 bv = *(const short8*)(W + ((size_t)kb * N + bn + j * 16 + r) * 8);
            acc[j] = __builtin_amdgcn_mfma_f32_16x16x32_bf16(av, bv, acc[j], 0, 0, 0);
        }
    }
#pragma unroll
    for (int j = 0; j < 4; ++j)
#pragma unroll
        for (int q = 0; q < 4; ++q) {
            const size_t idx = (size_t)(bm + kg * 4 + q) * N + bn + j * 16 + r;
            if constexpr (OUT16) ((short*)Cv)[idx] = f2bf(acc[j][q]);
            else                 ((float*)Cv)[idx] = acc[j][q];
        }
    if (STATS) {
#pragma unroll
        for (int j = 0; j < 4; ++j) {
            const float s = acc[j][0] + acc[j][1] + acc[j][2] + acc[j][3];
            const float q = acc[j][0]*acc[j][0] + acc[j][1]*acc[j][1]
                          + acc[j][2]*acc[j][2] + acc[j][3]*acc[j][3];
            atomicAdd(&ls[j * 16 + r], s);
            atomicAdd(&lq[j * 16 + r], q);
        }
        __syncthreads();
        if (threadIdx.x < 64) {
            atomicAdd(&gsum[bn + threadIdx.x], ls[threadIdx.x]);
            atomicAdd(&gsq[bn + threadIdx.x],  lq[threadIdx.x]);
        }
    }
}

// ---------------------------------------------------------------------------
// prep: k-block transforms of x, fc1_w, fc2_w (fp32 -> bf16), dw-weight
// transpose, grid-index + combined counts. Partitioned by blockIdx range.
// ---------------------------------------------------------------------------
constexpr int kXBlks  = kROWS * (kCIN / 8) / 256;        // 784
constexpr int kW1Blks = kCHID * (kCIN / 8) / 256;        // 32
constexpr int kW2Blks = kCOUT * (kCHID / 8) / 256;       // 32
constexpr int kWtBlks = (9 * 512 + 255) / 256;           // 18
constexpr int kCntBlks = kPTS / 256;                     // 196

__device__ __forceinline__ void cvt8_to(const float* __restrict__ in, short* __restrict__ out) {
    const float4 v0 = ((const float4*)in)[0];
    const float4 v1 = ((const float4*)in)[1];
    short8 o;
    o[0] = f2bf(v0.x); o[1] = f2bf(v0.y); o[2] = f2bf(v0.z); o[3] = f2bf(v0.w);
    o[4] = f2bf(v1.x); o[5] = f2bf(v1.y); o[6] = f2bf(v1.z); o[7] = f2bf(v1.w);
    *(short8*)out = o;
}

__global__ void prep_k(const float* __restrict__ x, short* __restrict__ xt,
                       const float* __restrict__ w1, short* __restrict__ w1t,
                       const float* __restrict__ w2, short* __restrict__ w2t,
                       const float* __restrict__ dww, short* __restrict__ wTb,
                       const float* __restrict__ loc, const int* __restrict__ iagg,
                       int* __restrict__ ihw, int* __restrict__ cnt)
{
    int blk = blockIdx.x;
    if (blk < kXBlks) {                       // x: [12544][128] -> k-block
        const int i = blk * 256 + threadIdx.x;
        const int m = i >> 4, kb = i & 15;
        cvt8_to(x + (size_t)m * kCIN + kb * 8, xt + ((size_t)kb * kROWS + m) * 8);
        return;
    }
    blk -= kXBlks;
    if (blk < kW1Blks) {                      // w1: [512][128] -> k-block
        const int i = blk * 256 + threadIdx.x;
        const int n = i >> 4, kb = i & 15;
        cvt8_to(w1 + (size_t)n * kCIN + kb * 8, w1t + ((size_t)kb * kCHID + n) * 8);
        return;
    }
    blk -= kW1Blks;
    if (blk < kW2Blks) {                      // w2: [128][512] -> k-block
        const int i = blk * 256 + threadIdx.x;
        const int n = i >> 6, kb = i & 63;
        cvt8_to(w2 + (size_t)n * kCHID + kb * 8, w2t + ((size_t)kb * kCOUT + n) * 8);
        return;
    }
    blk -= kW2Blks;
    if (blk < kWtBlks) {                      // dw weights: [512][9] -> [9][512]
        const int j = blk * 256 + threadIdx.x;
        if (j < 9 * 512) {
            const int tap = j / 512, ch = j % 512;
            wTb[j] = f2bf(dww[ch * 9 + tap]);
        }
        return;
    }
    blk -= kWtBlks;
    const int p = blk * 256 + threadIdx.x;    // grid-index + counts
    if (p >= kPTS) return;
    float lx = loc[(size_t)p * 2 + 0];
    float ly = loc[(size_t)p * 2 + 1];
    lx = fminf(fmaxf(lx, -1.f), 1.f) * 0.5f + 0.5f;
    ly = fminf(fmaxf(ly, -1.f), 1.f) * 0.5f + 0.5f;
    int gx = (int)rintf(lx * (float)(kW - 1)); gx = min(max(gx, 0), kW - 1);
    int gy = (int)rintf(ly * (float)(kH - 1)); gy = min(max(gy, 0), kH - 1);
    const int idx = gy * kW + gx;
    ihw[p] = idx;
    const int b = p / kN0;
    atomicAdd(cnt + b * kHW + idx, 1);
    atomicAdd(cnt + kBHW + b * kN + iagg[p], 1);
}

// ---------------------------------------------------------------------------
// scan1 + scan23. After fill_k, off[i] = segment END; seg i = [off[i-1], off[i]).
// ---------------------------------------------------------------------------
__global__ __launch_bounds__(256) void scan1_k(const int* __restrict__ cnt,
                                               int* __restrict__ off, int* __restrict__ bsum)
{
    __shared__ int sh[256];
    const int t = threadIdx.x;
    const int i = blockIdx.x * 256 + t;
    const int v = (i < kSEG) ? cnt[i] : 0;
    sh[t] = v; __syncthreads();
#pragma unroll
    for (int o = 1; o < 256; o <<= 1) {
        const int tmp = (t >= o) ? sh[t - o] : 0;
        __syncthreads();
        sh[t] += tmp;
        __syncthreads();
    }
    if (i < kSEG) off[i] = sh[t] - v;
    if (t == 255) bsum[blockIdx.x] = sh[255];
}

__global__ __launch_bounds__(256) void scan23_k(int* __restrict__ off,
                                                const int* __restrict__ bsum)
{
    __shared__ int sh[256];
    const int t = threadIdx.x;
    const int v = (t < kScanBlks) ? bsum[t] : 0;
    sh[t] = v; __syncthreads();
#pragma unroll
    for (int o = 1; o < 256; o <<= 1) {
        const int tmp = (t >= o) ? sh[t - o] : 0;
        __syncthreads();
        sh[t] += tmp;
        __syncthreads();
    }
    const int add = sh[blockIdx.x] - bsum[blockIdx.x];
    const int i = blockIdx.x * 256 + t;
    if (i < kSEG) off[i] += add;
}

__global__ void fill_k(const int* __restrict__ iagg, const int* __restrict__ ihw,
                       const float* __restrict__ aw, int* __restrict__ off,
                       int* __restrict__ slotA, float* __restrict__ w_all)
{
    const int p = blockIdx.x * 256 + threadIdx.x;
    if (p >= kPTS) return;
    const int b = p / kN0;
    const int tokrow = b * kN + iagg[p];
    const int cell   = b * kHW + ihw[p];
    const int cpos = atomicAdd(off + cell, 1);
    slotA[cpos] = tokrow;
    const int tpos = atomicAdd(off + kBHW + tokrow, 1);
    slotA[tpos] = cell;
    w_all[tpos] = aw[p];
}

// ---------------------------------------------------------------------------
// BN (inline coef, NP partial stat buffers summed) + GELU.
// KB=0: row-major out (for gathers). KB=1: k-block out (fc2's A operand).
// ---------------------------------------------------------------------------
template <int KB, int NP>
__global__ __launch_bounds__(256) void bn_act_b(
    const short* __restrict__ in, short* __restrict__ out,
    const float* __restrict__ gsum, const float* __restrict__ gsq,
    const float* __restrict__ g, const float* __restrict__ bb, float invn)
{
    __shared__ float ssc[512], ssh[512];
    {
        const int c = threadIdx.x * 2;
#pragma unroll
        for (int u = 0; u < 2; ++u) {
            float s = 0.f, q = 0.f;
#pragma unroll
            for (int p = 0; p < NP; ++p) {
                s += gsum[p * 512 + c + u];
                q += gsq[p * 512 + c + u];
            }
            const float m = s * invn;
            const float v = fmaxf(q * invn - m * m, 0.f);
            const float sc = g[c + u] * rsqrtf(v + kBEPS);
            ssc[c + u] = sc;
            ssh[c + u] = bb[c + u] - m * sc;
        }
    }
    __syncthreads();
    const size_t i = (size_t)blockIdx.x * 256 + threadIdx.x;   // over rows*512/8
    const int cg = (int)(i & 63);
    const int c0 = cg * 8;
    const size_t row = i >> 6;
    const short8 v = *(const short8*)(in + i * 8);
    short8 o;
#pragma unroll
    for (int j = 0; j < 8; ++j)
        o[j] = f2bf(gelu_f(fmaf(bf2f(v[j]), ssc[c0 + j], ssh[c0 + j])));
    if constexpr (KB) *(short8*)(out + ((size_t)cg * kROWS + row) * 8) = o;
    else              *(short8*)(out + i * 8) = o;
}

__global__ __launch_bounds__(256) void bn_act_f128(
    const float* __restrict__ in, float* __restrict__ out,
    const float* __restrict__ gsum, const float* __restrict__ gsq,
    const float* __restrict__ g, const float* __restrict__ bb, float invn)
{
    __shared__ float ssc[128], ssh[128];
    if (threadIdx.x < 128) {
        const int c = threadIdx.x;
        const float m = gsum[c] * invn;
        const float v = fmaxf(gsq[c] * invn - m * m, 0.f);
        const float sc = g[c] * rsqrtf(v + kBEPS);
        ssc[c] = sc;
        ssh[c] = bb[c] - m * sc;
    }
    __syncthreads();
    const size_t i = (size_t)blockIdx.x * 256 + threadIdx.x;   // over rows*128/4
    const int c0 = (int)(i & 31) * 4;
    float4 v = ((const float4*)in)[i];
    v.x = gelu_f(fmaf(v.x, ssc[c0 + 0], ssh[c0 + 0]));
    v.y = gelu_f(fmaf(v.y, ssc[c0 + 1], ssh[c0 + 1]));
    v.z = gelu_f(fmaf(v.z, ssc[c0 + 2], ssh[c0 + 2]));
    v.w = gelu_f(fmaf(v.w, ssc[c0 + 3], ssh[c0 + 3]));
    ((float4*)out)[i] = v;
}

// ---------------------------------------------------------------------------
// token2map gather (bf16, post-BN1): one wave per cell, 8 ch/lane. Empty -> 0.
// ---------------------------------------------------------------------------
__global__ __launch_bounds__(256) void gather_map_b(
    const short* __restrict__ hb, const int* __restrict__ off,
    const int* __restrict__ toklist, short* __restrict__ smap)
{
    const int lane = threadIdx.x & 63;
    const int cell = blockIdx.x * 4 + (threadIdx.x >> 6);
    const int s = cell ? off[cell - 1] : 0;
    const int e = off[cell];
    const int c0 = lane * 8;
    float a[8] = {};
    int j = s;
    for (; j + 1 < e; j += 2) {
        const int t0 = toklist[j], t1 = toklist[j + 1];
        const short8 v0 = *(const short8*)(hb + (size_t)t0 * kCHID + c0);
        const short8 v1 = *(const short8*)(hb + (size_t)t1 * kCHID + c0);
#pragma unroll
        for (int t = 0; t < 8; ++t) a[t] += bf2f(v0[t]) + bf2f(v1[t]);
    }
    if (j < e) {
        const short8 v = *(const short8*)(hb + (size_t)toklist[j] * kCHID + c0);
#pragma unroll
        for (int t = 0; t < 8; ++t) a[t] += bf2f(v[t]);
    }
    const float sc = 1.f / ((float)(e - s) + kEPS);
    short8 o;
#pragma unroll
    for (int t = 0; t < 8; ++t) o[t] = f2bf(a[t] * sc);
    *(short8*)(smap + (size_t)cell * kCHID + c0) = o;
}

// ---------------------------------------------------------------------------
// Depthwise 3x3 bf16, zero-filled map. 2x2 cells x 8 ch per thread.
// XCD-chunked blockIdx swizzle (T1).
// ---------------------------------------------------------------------------
__global__ __launch_bounds__(256) void dwconv_b(
    const short* __restrict__ smap, const int* __restrict__ cnt,
    const short* __restrict__ wTb, const float* __restrict__ bdw,
    short* __restrict__ convo)
{
    constexpr int kTX = kW / 2;                 // 56
    constexpr int kChunk = kDwBlks / 8;         // 392
    const int wg = (blockIdx.x & 7) * kChunk + (blockIdx.x >> 3);
    const int c8 = threadIdx.x & 63;
    const int w  = wg * 4 + (threadIdx.x >> 6);
    const int b   = w / (kTX * kTX);
    const int rem = w % (kTX * kTX);
    const int ty = rem / kTX, tx = rem % kTX;
    const int y0 = ty * 2, x0 = tx * 2;
    const int gbase = b * kHW;
    const int c0 = c8 * 8;

    const int cell00 = gbase + y0 * kW + x0;    // even -> int2 aligned
    const int2 nA = *(const int2*)(cnt + cell00);
    const int2 nB = *(const int2*)(cnt + cell00 + kW);
    const int n00 = nA.x, n01 = nA.y, n10 = nB.x, n11 = nB.y;
    if ((n00 | n01 | n10 | n11) == 0) return;

    float wf[9][8];
#pragma unroll
    for (int t = 0; t < 9; ++t) {
        const short8 wv = *(const short8*)(wTb + t * kCHID + c0);
#pragma unroll
        for (int j = 0; j < 8; ++j) wf[t][j] = bf2f(wv[j]);
    }
    float bz[8];
    {
        const float4 b0 = *(const float4*)(bdw + c0);
        const float4 b1 = *(const float4*)(bdw + c0 + 4);
        bz[0] = b0.x; bz[1] = b0.y; bz[2] = b0.z; bz[3] = b0.w;
        bz[4] = b1.x; bz[5] = b1.y; bz[6] = b1.z; bz[7] = b1.w;
    }
    float acc[2][2][8];
#pragma unroll
    for (int cy = 0; cy < 2; ++cy)
#pragma unroll
        for (int cx = 0; cx < 2; ++cx)
#pragma unroll
            for (int j = 0; j < 8; ++j) acc[cy][cx][j] = bz[j];

#pragma unroll
    for (int dy = 0; dy < 4; ++dy) {
        const int yy = y0 - 1 + dy;
        if ((unsigned)yy >= (unsigned)kH) continue;
#pragma unroll
        for (int dx = 0; dx < 4; ++dx) {
            const int xx = x0 - 1 + dx;
            if ((unsigned)xx >= (unsigned)kW) continue;
            const short8 tv = *(const short8*)(smap + (size_t)(gbase + yy * kW + xx) * kCHID + c0);
            float tf[8];
#pragma unroll
            for (int j = 0; j < 8; ++j) tf[j] = bf2f(tv[j]);
#pragma unroll
            for (int cy = 0; cy < 2; ++cy) {
                const int wy = dy - cy;
                if ((unsigned)wy >= 3u) continue;
#pragma unroll
                for (int cx = 0; cx < 2; ++cx) {
                    const int wx = dx - cx;
                    if ((unsigned)wx >= 3u) continue;
                    const float* wq = wf[wy * 3 + wx];
#pragma unroll
                    for (int j = 0; j < 8; ++j)
                        acc[cy][cx][j] = fmaf(wq[j], tf[j], acc[cy][cx][j]);
                }
            }
        }
    }
#pragma unroll
    for (int cy = 0; cy < 2; ++cy)
#pragma unroll
        for (int cx = 0; cx < 2; ++cx) {
            const int n = (cy == 0) ? (cx == 0 ? n00 : n01) : (cx == 0 ? n10 : n11);
            if (!n) continue;
            short8 o;
#pragma unroll
            for (int j = 0; j < 8; ++j) o[j] = f2bf(acc[cy][cx][j]);
            *(short8*)(convo + (size_t)(cell00 + cy * kW + cx) * kCHID + c0) = o;
        }
}

// ---------------------------------------------------------------------------
// map2token gather + fused skip + FUSED BN2 stats into 8-way partials.
// 1 row per wave, unrolled x2. Contention: 3136 blocks / 8 partials = 392
// writers per address (R6: 784 OK, R7: 3136 BAD — 392 is safe).
// ---------------------------------------------------------------------------
__global__ __launch_bounds__(256) void gather_tok_b(
    const short* __restrict__ convo, const int* __restrict__ off,
    const int* __restrict__ celllist, const float* __restrict__ wlist,
    const short* __restrict__ hb, const float* __restrict__ dws,
    short* __restrict__ h2, float* __restrict__ gsum2p, float* __restrict__ gsq2p)
{
    __shared__ float shs[4][512];
    __shared__ float shq[4][512];
    const int lane = threadIdx.x & 63;
    const int wave = threadIdx.x >> 6;
    const int t = blockIdx.x * 4 + wave;
    const int seg = kBHW + t;                      // token segments follow cells
    const int sbeg = off[seg - 1], send = off[seg];
    const int c0 = lane * 8;
    const short8 hv = *(const short8*)(hb + (size_t)t * kCHID + c0);
    const float4 d0 = *(const float4*)(dws + c0);
    const float4 d1 = *(const float4*)(dws + c0 + 4);
    const float dd[8] = {d0.x, d0.y, d0.z, d0.w, d1.x, d1.y, d1.z, d1.w};
    float a[8] = {};
    float den = 0.f;
    int j = sbeg;
    for (; j + 1 < send; j += 2) {
        const float w0 = wlist[j], w1 = wlist[j + 1];
        const int   cA = celllist[j], cBn = celllist[j + 1];
        den += w0 + w1;
        const short8 v0 = *(const short8*)(convo + (size_t)cA  * kCHID + c0);
        const short8 v1 = *(const short8*)(convo + (size_t)cBn * kCHID + c0);
#pragma unroll
        for (int k = 0; k < 8; ++k)
            a[k] += w0 * bf2f(v0[k]) + w1 * bf2f(v1[k]);
    }
    if (j < send) {
        const float w = wlist[j];
        den += w;
        const short8 v = *(const short8*)(convo + (size_t)celllist[j] * kCHID + c0);
#pragma unroll
        for (int k = 0; k < 8; ++k) a[k] = fmaf(w, bf2f(v[k]), a[k]);
    }
    const float r = 1.f / (den + kEPS);
    short8 o;
#pragma unroll
    for (int k = 0; k < 8; ++k) {
        const float val = fmaf(bf2f(hv[k]), dd[k], a[k] * r);
        o[k] = f2bf(val);
        shs[wave][c0 + k] = val;
        shq[wave][c0 + k] = val * val;
    }
    *(short8*)(h2 + (size_t)t * kCHID + c0) = o;
    __syncthreads();
    const int c = threadIdx.x * 2;
    const int part = (blockIdx.x & 7) * 512;
    const float s0 = shs[0][c] + shs[1][c] + shs[2][c] + shs[3][c];
    const float s1 = shs[0][c+1] + shs[1][c+1] + shs[2][c+1] + shs[3][c+1];
    const float q0 = shq[0][c] + shq[1][c] + shq[2][c] + shq[3][c];
    const float q1 = shq[0][c+1] + shq[1][c+1] + shq[2][c+1] + shq[3][c+1];
    atomicAdd(&gsum2p[part + c], s0);   atomicAdd(&gsum2p[part + c + 1], s1);
    atomicAdd(&gsq2p[part + c],  q0);   atomicAdd(&gsq2p[part + c + 1],  q1);
}

// ---------------------------------------------------------------------------
extern "C" void kernel_launch(void* const* d_in, const int* in_sizes, int n_in,
                              void* d_out, int out_size, void* d_ws, size_t ws_size,
                              hipStream_t stream)
{
    (void)in_sizes; (void)n_in; (void)out_size; (void)ws_size;
    const float* x    = (const float*)d_in[0];
    const float* loc  = (const float*)d_in[1];
    const int*   iagg = (const int*)  d_in[2];
    const float* aw   = (const float*)d_in[3];
    const float* fc1w = (const float*)d_in[4];
    const float* fc1b = (const float*)d_in[5];
    const float* g1   = (const float*)d_in[6];
    const float* b1   = (const float*)d_in[7];
    const float* dww  = (const float*)d_in[8];
    const float* dwb  = (const float*)d_in[9];
    const float* dwsw = (const float*)d_in[10];
    const float* g2   = (const float*)d_in[11];
    const float* b2   = (const float*)d_in[12];
    const float* fc2w = (const float*)d_in[13];
    const float* fc2b = (const float*)d_in[14];
    const float* g3   = (const float*)d_in[15];
    const float* b3   = (const float*)d_in[16];
    float* outp = (float*)d_out;

    float* ws = (float*)d_ws;
    // --- zeroed region: BN stats (incl. 8-way BN2 partials) + counts ---
    float* gsum1  = ws + 0;            // 512
    float* gsq1   = ws + 512;          // 512
    float* gsum2p = ws + 1024;         // 8*512 = 4096
    float* gsq2p  = ws + 5120;         // 4096
    float* gsum3  = ws + 9216;         // 128
    float* gsq3   = ws + 9344;         // 128
    int* cnt = (int*)(ws + 9472);      // [kSEG]
    const size_t zero_bytes = (9472ull + kSEG) * 4;
    // --- non-zeroed (word offsets keep 16B alignment for short8 arrays) ---
    int*   off   = cnt + kSEG;                       // [kSEG] (+pad) -> 62724
    int*   bsum  = off + 62724;                      // [256]
    int*   ihw   = bsum + 256;                       // [kPTS]
    int*   slotA = ihw + kPTS;                       // [2*kPTS]
    float* w_all = (float*)(slotA + 2 * kPTS);       // [2*kPTS]
    short* wTb   = (short*)(w_all + 2 * kPTS);       // [4608]
    short* xt    = wTb + 4608;                       // [kROWS*kCIN] k-block
    short* w1t   = xt + (size_t)kROWS * kCIN;        // [512*128] k-block
    short* w2t   = w1t + 512 * 128;                  // [128*512] k-block
    short* hraw  = w2t + 128 * 512;                  // bf16 [kROWS][512] row-major
    short* hb16  = hraw + (size_t)kROWS * kCHID;     // bf16: BN1 row-major, then BN2 k-block
    short* smap  = hb16 + (size_t)kROWS * kCHID;     // bf16 [kBHW][512]
    short* convo = smap + (size_t)kBHW * kCHID;      // bf16 [kBHW][512]
    float* out3  = (float*)smap;                     // alias: smap dead after dwconv

    hipMemsetAsync(ws, 0, zero_bytes, stream);

    // prep: k-block transforms (x, w1, w2) + dw transpose + grid-index/counts
    prep_k<<<kXBlks + kW1Blks + kW2Blks + kWtBlks + kCntBlks, 256, 0, stream>>>(
        x, xt, fc1w, w1t, fc2w, w2t, dww, wTb, loc, iagg, ihw, cnt);

    // fc1 (k-block operands; MFMA -> bf16 row-major) + fused BN1 stats
    gemm_kb_k<1, 1><<<dim3(kROWS / 64, kCHID / 64), 256, 0, stream>>>(
        xt, w1t, fc1b, hraw, gsum1, gsq1, kROWS, kCHID, kCIN);

    // CSR scan (2 kernels) + fill
    scan1_k<<<kScanBlks, 256, 0, stream>>>(cnt, off, bsum);
    scan23_k<<<kScanBlks, 256, 0, stream>>>(off, bsum);
    fill_k<<<kPTS / 256, 256, 0, stream>>>(iagg, ihw, aw, off, slotA, w_all);

    // BN1 + GELU (row-major: feeds both gathers)
    bn_act_b<0, 1><<<(kROWS * kCHID / 8) / 256, 256, 0, stream>>>(
        hraw, hb16, gsum1, gsq1, g1, b1, 1.f / kROWS);

    // token -> map (zero-filled) -> dwconv (XCD-banded)
    gather_map_b<<<kBHW / 4, 256, 0, stream>>>(hb16, off, slotA, smap);
    dwconv_b<<<kDwBlks, 256, 0, stream>>>(smap, cnt, wTb, dwb, convo);

    // map -> token (+fused skip + BN2 stats into 8-way partials), h2 -> hraw
    gather_tok_b<<<kROWS / 4, 256, 0, stream>>>(convo, off, slotA, w_all,
                                                hb16, dwsw, hraw, gsum2p, gsq2p);

    // BN2 + GELU -> k-block layout (fc2's A operand); coefs sum the 8 partials
    bn_act_b<1, 8><<<(kROWS * kCHID / 8) / 256, 256, 0, stream>>>(
        hraw, hb16, gsum2p, gsq2p, g2, b2, 1.f / kROWS);

    // fc2 (k-block operands; MFMA -> fp32) + fused BN3 stats
    gemm_kb_k<0, 1><<<dim3(kROWS / 64, kCOUT / 64), 256, 0, stream>>>(
        hb16, w2t, fc2b, out3, gsum3, gsq3, kROWS, kCOUT, kCHID);

    // BN3 + GELU -> out (fp32)
    bn_act_f128<<<(kROWS * kCOUT / 4) / 256, 256, 0, stream>>>(
        out3, outp, gsum3, gsq3, g3, b3, 1.f / kROWS);
}

// Round 17
// 171.188 us; speedup vs baseline: 1.0220x; 1.0220x over previous
//
#include <hip/hip_runtime.h>
#include <math.h>

// Problem constants (fixed by the reference)
constexpr int kB    = 4;
constexpr int kN    = 3136;
constexpr int kN0   = 12544;
constexpr int kH    = 112, kW = 112;
constexpr int kHW   = kH * kW;          // 12544
constexpr int kCIN  = 128;
constexpr int kCHID = 512;
constexpr int kCOUT = 128;
constexpr int kROWS = kB * kN;          // 12544
constexpr int kPTS  = kB * kN0;         // 50176
constexpr int kBHW  = kB * kHW;         // 50176
constexpr int kSEG  = kBHW + kROWS;     // 62720 combined CSR segments
constexpr int kScanBlks = (kSEG + 255) / 256;   // 245
constexpr int kDwBlks   = kB * kHW / 16;        // 3136 (multiple of 8)
constexpr int kGmBlks   = kBHW / 4;             // 12544 (multiple of 8)
constexpr float kEPS  = 1e-6f;
constexpr float kBEPS = 1e-5f;

typedef __attribute__((ext_vector_type(8))) short short8;
typedef __attribute__((ext_vector_type(4))) float f32x4;

__device__ __forceinline__ float gelu_f(float x) {
    return 0.5f * x * (1.0f + erff(x * 0.70710678118654752440f));
}
__device__ __forceinline__ float bf2f(short s) {
    union { unsigned u; float f; } v; v.u = ((unsigned)(unsigned short)s) << 16; return v.f;
}
__device__ __forceinline__ short f2bf(float f) {
    union { float f; unsigned u; } v; v.f = f;
    const unsigned r = v.u + 0x7fffu + ((v.u >> 16) & 1u);   // RNE
    return (short)(r >> 16);
}

// Build BN scale/shift for 512 channels into LDS (256 threads x 2 channels).
__device__ __forceinline__ void bn_coef_lds(
    const float* __restrict__ gsum, const float* __restrict__ gsq,
    const float* __restrict__ g, const float* __restrict__ bb,
    float invn, float* ssc, float* ssh)
{
    const int c = threadIdx.x * 2;
#pragma unroll
    for (int u = 0; u < 2; ++u) {
        const float m = gsum[c + u] * invn;
        const float v = fmaxf(gsq[c + u] * invn - m * m, 0.f);
        const float sc = g[c + u] * rsqrtf(v + kBEPS);
        ssc[c + u] = sc;
        ssh[c + u] = bb[c + u] - m * sc;
    }
}

// ---------------------------------------------------------------------------
// MFMA bf16 GEMM, K-BLOCK operand layout:  T[(k/8)*dim + idx][8].
// (R14 lesson: row-major fragment loads are address-divergent; k-block makes
//  16 lanes contiguous -> fixed 44us/1.3% MfmaUtil GEMMs.)
// Fused per-column stats (196 writers/addr = fine; R7: never 3136 writers).
// ---------------------------------------------------------------------------
template <int OUT16, int STATS>
__global__ __launch_bounds__(256) void gemm_kb_k(
    const short* __restrict__ A, const short* __restrict__ W,
    const float* __restrict__ bias, void* __restrict__ Cv,
    float* __restrict__ gsum, float* __restrict__ gsq,
    int M, int N, int K)
{
    __shared__ float ls[64], lq[64];
    if (STATS) {
        if (threadIdx.x < 64) { ls[threadIdx.x] = 0.f; lq[threadIdx.x] = 0.f; }
        __syncthreads();
    }
    const int wave = threadIdx.x >> 6;
    const int lane = threadIdx.x & 63;
    const int r = lane & 15, kg = lane >> 4;
    const int bm = blockIdx.x * 64 + wave * 16;
    const int bn = blockIdx.y * 64;
    f32x4 acc[4];
#pragma unroll
    for (int j = 0; j < 4; ++j) {
        const float bz = bias[bn + j * 16 + r];
        acc[j][0] = bz; acc[j][1] = bz; acc[j][2] = bz; acc[j][3] = bz;
    }
    for (int k0 = 0; k0 < K; k0 += 32) {
        const int kb = (k0 >> 3) + kg;
        const short8 av = *(const short8*)(A + ((size_t)kb * M + bm + r) * 8);
#pragma unroll
        for (int j = 0; j < 4; ++j) {
            const short8 bv = *(const short8*)(W + ((size_t)kb * N + bn + j * 16 + r) * 8);
            acc[j] = __builtin_amdgcn_mfma_f32_16x16x32_bf16(av, bv, acc[j], 0, 0, 0);
        }
    }
#pragma unroll
    for (int j = 0; j < 4; ++j)
#pragma unroll
        for (int q = 0; q < 4; ++q) {
            const size_t idx = (size_t)(bm + kg * 4 + q) * N + bn + j * 16 + r;
            if constexpr (OUT16) ((short*)Cv)[idx] = f2bf(acc[j][q]);
            else                 ((float*)Cv)[idx] = acc[j][q];
        }
    if (STATS) {
#pragma unroll
        for (int j = 0; j < 4; ++j) {
            const float s = acc[j][0] + acc[j][1] + acc[j][2] + acc[j][3];
            const float q = acc[j][0]*acc[j][0] + acc[j][1]*acc[j][1]
                          + acc[j][2]*acc[j][2] + acc[j][3]*acc[j][3];
            atomicAdd(&ls[j * 16 + r], s);
            atomicAdd(&lq[j * 16 + r], q);
        }
        __syncthreads();
        if (threadIdx.x < 64) {
            atomicAdd(&gsum[bn + threadIdx.x], ls[threadIdx.x]);
            atomicAdd(&gsq[bn + threadIdx.x],  lq[threadIdx.x]);
        }
    }
}

// ---------------------------------------------------------------------------
// prep: k-block transforms of x, fc1_w, fc2_w (fp32 -> bf16), dw-weight
// transpose, grid-index + combined counts. Partitioned by blockIdx range.
// ---------------------------------------------------------------------------
constexpr int kXBlks  = kROWS * (kCIN / 8) / 256;        // 784
constexpr int kW1Blks = kCHID * (kCIN / 8) / 256;        // 32
constexpr int kW2Blks = kCOUT * (kCHID / 8) / 256;       // 32
constexpr int kWtBlks = (9 * 512 + 255) / 256;           // 18
constexpr int kCntBlks = kPTS / 256;                     // 196

__device__ __forceinline__ void cvt8_to(const float* __restrict__ in, short* __restrict__ out) {
    const float4 v0 = ((const float4*)in)[0];
    const float4 v1 = ((const float4*)in)[1];
    short8 o;
    o[0] = f2bf(v0.x); o[1] = f2bf(v0.y); o[2] = f2bf(v0.z); o[3] = f2bf(v0.w);
    o[4] = f2bf(v1.x); o[5] = f2bf(v1.y); o[6] = f2bf(v1.z); o[7] = f2bf(v1.w);
    *(short8*)out = o;
}

__global__ void prep_k(const float* __restrict__ x, short* __restrict__ xt,
                       const float* __restrict__ w1, short* __restrict__ w1t,
                       const float* __restrict__ w2, short* __restrict__ w2t,
                       const float* __restrict__ dww, short* __restrict__ wTb,
                       const float* __restrict__ loc, const int* __restrict__ iagg,
                       int* __restrict__ ihw, int* __restrict__ cnt)
{
    int blk = blockIdx.x;
    if (blk < kXBlks) {                       // x: [12544][128] -> k-block
        const int i = blk * 256 + threadIdx.x;
        const int m = i >> 4, kb = i & 15;
        cvt8_to(x + (size_t)m * kCIN + kb * 8, xt + ((size_t)kb * kROWS + m) * 8);
        return;
    }
    blk -= kXBlks;
    if (blk < kW1Blks) {                      // w1: [512][128] -> k-block
        const int i = blk * 256 + threadIdx.x;
        const int n = i >> 4, kb = i & 15;
        cvt8_to(w1 + (size_t)n * kCIN + kb * 8, w1t + ((size_t)kb * kCHID + n) * 8);
        return;
    }
    blk -= kW1Blks;
    if (blk < kW2Blks) {                      // w2: [128][512] -> k-block
        const int i = blk * 256 + threadIdx.x;
        const int n = i >> 6, kb = i & 63;
        cvt8_to(w2 + (size_t)n * kCHID + kb * 8, w2t + ((size_t)kb * kCOUT + n) * 8);
        return;
    }
    blk -= kW2Blks;
    if (blk < kWtBlks) {                      // dw weights: [512][9] -> [9][512]
        const int j = blk * 256 + threadIdx.x;
        if (j < 9 * 512) {
            const int tap = j / 512, ch = j % 512;
            wTb[j] = f2bf(dww[ch * 9 + tap]);
        }
        return;
    }
    blk -= kWtBlks;
    const int p = blk * 256 + threadIdx.x;    // grid-index + counts
    if (p >= kPTS) return;
    float lx = loc[(size_t)p * 2 + 0];
    float ly = loc[(size_t)p * 2 + 1];
    lx = fminf(fmaxf(lx, -1.f), 1.f) * 0.5f + 0.5f;
    ly = fminf(fmaxf(ly, -1.f), 1.f) * 0.5f + 0.5f;
    int gx = (int)rintf(lx * (float)(kW - 1)); gx = min(max(gx, 0), kW - 1);
    int gy = (int)rintf(ly * (float)(kH - 1)); gy = min(max(gy, 0), kH - 1);
    const int idx = gy * kW + gx;
    ihw[p] = idx;
    const int b = p / kN0;
    atomicAdd(cnt + b * kHW + idx, 1);
    atomicAdd(cnt + kBHW + b * kN + iagg[p], 1);
}

// ---------------------------------------------------------------------------
// scan1 + scan23. After fill_k, off[i] = segment END; seg i = [off[i-1], off[i]).
// ---------------------------------------------------------------------------
__global__ __launch_bounds__(256) void scan1_k(const int* __restrict__ cnt,
                                               int* __restrict__ off, int* __restrict__ bsum)
{
    __shared__ int sh[256];
    const int t = threadIdx.x;
    const int i = blockIdx.x * 256 + t;
    const int v = (i < kSEG) ? cnt[i] : 0;
    sh[t] = v; __syncthreads();
#pragma unroll
    for (int o = 1; o < 256; o <<= 1) {
        const int tmp = (t >= o) ? sh[t - o] : 0;
        __syncthreads();
        sh[t] += tmp;
        __syncthreads();
    }
    if (i < kSEG) off[i] = sh[t] - v;
    if (t == 255) bsum[blockIdx.x] = sh[255];
}

__global__ __launch_bounds__(256) void scan23_k(int* __restrict__ off,
                                                const int* __restrict__ bsum)
{
    __shared__ int sh[256];
    const int t = threadIdx.x;
    const int v = (t < kScanBlks) ? bsum[t] : 0;
    sh[t] = v; __syncthreads();
#pragma unroll
    for (int o = 1; o < 256; o <<= 1) {
        const int tmp = (t >= o) ? sh[t - o] : 0;
        __syncthreads();
        sh[t] += tmp;
        __syncthreads();
    }
    const int add = sh[blockIdx.x] - bsum[blockIdx.x];
    const int i = blockIdx.x * 256 + t;
    if (i < kSEG) off[i] += add;
}

__global__ void fill_k(const int* __restrict__ iagg, const int* __restrict__ ihw,
                       const float* __restrict__ aw, int* __restrict__ off,
                       int* __restrict__ slotA, float* __restrict__ w_all)
{
    const int p = blockIdx.x * 256 + threadIdx.x;
    if (p >= kPTS) return;
    const int b = p / kN0;
    const int tokrow = b * kN + iagg[p];
    const int cell   = b * kHW + ihw[p];
    const int cpos = atomicAdd(off + cell, 1);
    slotA[cpos] = tokrow;
    const int tpos = atomicAdd(off + kBHW + tokrow, 1);
    slotA[tpos] = cell;
    w_all[tpos] = aw[p];
}

// ---------------------------------------------------------------------------
// Column stats over bf16 [rows][512] (196 blocks -> low atomic contention).
// ---------------------------------------------------------------------------
__global__ __launch_bounds__(256) void colstats_b(
    const short* __restrict__ X, float* __restrict__ gsum, float* __restrict__ gsq,
    int rows_per_blk)
{
    __shared__ float shs[4][512];
    __shared__ float shq[4][512];
    const int g = threadIdx.x & 63;
    const int rr = threadIdx.x >> 6;
    const int r0 = blockIdx.x * rows_per_blk;
    float s[8] = {}, q[8] = {};
    for (int r = rr; r < rows_per_blk; r += 4) {
        const short8 v = *(const short8*)(X + (size_t)(r0 + r) * kCHID + g * 8);
#pragma unroll
        for (int j = 0; j < 8; ++j) { const float f = bf2f(v[j]); s[j] += f; q[j] += f * f; }
    }
#pragma unroll
    for (int j = 0; j < 8; ++j) { shs[rr][g * 8 + j] = s[j]; shq[rr][g * 8 + j] = q[j]; }
    __syncthreads();
    const int c = threadIdx.x * 2;
    const float s0 = shs[0][c] + shs[1][c] + shs[2][c] + shs[3][c];
    const float s1 = shs[0][c+1] + shs[1][c+1] + shs[2][c+1] + shs[3][c+1];
    const float q0 = shq[0][c] + shq[1][c] + shq[2][c] + shq[3][c];
    const float q1 = shq[0][c+1] + shq[1][c+1] + shq[2][c+1] + shq[3][c+1];
    atomicAdd(&gsum[c], s0);   atomicAdd(&gsum[c+1], s1);
    atomicAdd(&gsq[c],  q0);   atomicAdd(&gsq[c+1],  q1);
}

// ---------------------------------------------------------------------------
// BN (inline coef) + GELU passes.
// KB=0: row-major out (for gathers). KB=1: k-block out (fc2's A operand).
// ---------------------------------------------------------------------------
template <int KB>
__global__ __launch_bounds__(256) void bn_act_b(
    const short* __restrict__ in, short* __restrict__ out,
    const float* __restrict__ gsum, const float* __restrict__ gsq,
    const float* __restrict__ g, const float* __restrict__ bb, float invn)
{
    __shared__ float ssc[512], ssh[512];
    bn_coef_lds(gsum, gsq, g, bb, invn, ssc, ssh);
    __syncthreads();
    const size_t i = (size_t)blockIdx.x * 256 + threadIdx.x;   // over rows*512/8
    const int cg = (int)(i & 63);
    const int c0 = cg * 8;
    const size_t row = i >> 6;
    const short8 v = *(const short8*)(in + i * 8);
    short8 o;
#pragma unroll
    for (int j = 0; j < 8; ++j)
        o[j] = f2bf(gelu_f(fmaf(bf2f(v[j]), ssc[c0 + j], ssh[c0 + j])));
    if constexpr (KB) *(short8*)(out + ((size_t)cg * kROWS + row) * 8) = o;
    else              *(short8*)(out + i * 8) = o;
}

__global__ __launch_bounds__(256) void bn_act_f128(
    const float* __restrict__ in, float* __restrict__ out,
    const float* __restrict__ gsum, const float* __restrict__ gsq,
    const float* __restrict__ g, const float* __restrict__ bb, float invn)
{
    __shared__ float ssc[128], ssh[128];
    if (threadIdx.x < 128) {
        const int c = threadIdx.x;
        const float m = gsum[c] * invn;
        const float v = fmaxf(gsq[c] * invn - m * m, 0.f);
        const float sc = g[c] * rsqrtf(v + kBEPS);
        ssc[c] = sc;
        ssh[c] = bb[c] - m * sc;
    }
    __syncthreads();
    const size_t i = (size_t)blockIdx.x * 256 + threadIdx.x;   // over rows*128/4
    const int c0 = (int)(i & 31) * 4;
    float4 v = ((const float4*)in)[i];
    v.x = gelu_f(fmaf(v.x, ssc[c0 + 0], ssh[c0 + 0]));
    v.y = gelu_f(fmaf(v.y, ssc[c0 + 1], ssh[c0 + 1]));
    v.z = gelu_f(fmaf(v.z, ssc[c0 + 2], ssh[c0 + 2]));
    v.w = gelu_f(fmaf(v.w, ssc[c0 + 3], ssh[c0 + 3]));
    ((float4*)out)[i] = v;
}

// ---------------------------------------------------------------------------
// token2map gather (bf16, post-BN1): one wave per cell, 8 ch/lane. Empty -> 0.
// XCD-banded (same mapping as dwconv): XCD j writes the y-band that dwconv's
// XCD j reads -> smap handoff stays in that XCD's L2 instead of HBM.
// ---------------------------------------------------------------------------
__global__ __launch_bounds__(256) void gather_map_b(
    const short* __restrict__ hb, const int* __restrict__ off,
    const int* __restrict__ toklist, short* __restrict__ smap)
{
    constexpr int kChunkG = kGmBlks / 8;        // 1568
    const int wg = (blockIdx.x & 7) * kChunkG + (blockIdx.x >> 3);
    const int lane = threadIdx.x & 63;
    const int cell = wg * 4 + (threadIdx.x >> 6);
    const int s = cell ? off[cell - 1] : 0;
    const int e = off[cell];
    const int c0 = lane * 8;
    float a[8] = {};
    int j = s;
    for (; j + 1 < e; j += 2) {
        const int t0 = toklist[j], t1 = toklist[j + 1];
        const short8 v0 = *(const short8*)(hb + (size_t)t0 * kCHID + c0);
        const short8 v1 = *(const short8*)(hb + (size_t)t1 * kCHID + c0);
#pragma unroll
        for (int t = 0; t < 8; ++t) a[t] += bf2f(v0[t]) + bf2f(v1[t]);
    }
    if (j < e) {
        const short8 v = *(const short8*)(hb + (size_t)toklist[j] * kCHID + c0);
#pragma unroll
        for (int t = 0; t < 8; ++t) a[t] += bf2f(v[t]);
    }
    const float sc = 1.f / ((float)(e - s) + kEPS);
    short8 o;
#pragma unroll
    for (int t = 0; t < 8; ++t) o[t] = f2bf(a[t] * sc);
    *(short8*)(smap + (size_t)cell * kCHID + c0) = o;
}

// ---------------------------------------------------------------------------
// Depthwise 3x3 bf16, zero-filled map. 2x2 cells x 8 ch per thread.
// XCD-chunked blockIdx swizzle (T1).
// ---------------------------------------------------------------------------
__global__ __launch_bounds__(256) void dwconv_b(
    const short* __restrict__ smap, const int* __restrict__ cnt,
    const short* __restrict__ wTb, const float* __restrict__ bdw,
    short* __restrict__ convo)
{
    constexpr int kTX = kW / 2;                 // 56
    constexpr int kChunk = kDwBlks / 8;         // 392
    const int wg = (blockIdx.x & 7) * kChunk + (blockIdx.x >> 3);
    const int c8 = threadIdx.x & 63;
    const int w  = wg * 4 + (threadIdx.x >> 6);
    const int b   = w / (kTX * kTX);
    const int rem = w % (kTX * kTX);
    const int ty = rem / kTX, tx = rem % kTX;
    const int y0 = ty * 2, x0 = tx * 2;
    const int gbase = b * kHW;
    const int c0 = c8 * 8;

    const int cell00 = gbase + y0 * kW + x0;    // even -> int2 aligned
    const int2 nA = *(const int2*)(cnt + cell00);
    const int2 nB = *(const int2*)(cnt + cell00 + kW);
    const int n00 = nA.x, n01 = nA.y, n10 = nB.x, n11 = nB.y;
    if ((n00 | n01 | n10 | n11) == 0) return;

    float wf[9][8];
#pragma unroll
    for (int t = 0; t < 9; ++t) {
        const short8 wv = *(const short8*)(wTb + t * kCHID + c0);
#pragma unroll
        for (int j = 0; j < 8; ++j) wf[t][j] = bf2f(wv[j]);
    }
    float bz[8];
    {
        const float4 b0 = *(const float4*)(bdw + c0);
        const float4 b1 = *(const float4*)(bdw + c0 + 4);
        bz[0] = b0.x; bz[1] = b0.y; bz[2] = b0.z; bz[3] = b0.w;
        bz[4] = b1.x; bz[5] = b1.y; bz[6] = b1.z; bz[7] = b1.w;
    }
    float acc[2][2][8];
#pragma unroll
    for (int cy = 0; cy < 2; ++cy)
#pragma unroll
        for (int cx = 0; cx < 2; ++cx)
#pragma unroll
            for (int j = 0; j < 8; ++j) acc[cy][cx][j] = bz[j];

#pragma unroll
    for (int dy = 0; dy < 4; ++dy) {
        const int yy = y0 - 1 + dy;
        if ((unsigned)yy >= (unsigned)kH) continue;
#pragma unroll
        for (int dx = 0; dx < 4; ++dx) {
            const int xx = x0 - 1 + dx;
            if ((unsigned)xx >= (unsigned)kW) continue;
            const short8 tv = *(const short8*)(smap + (size_t)(gbase + yy * kW + xx) * kCHID + c0);
            float tf[8];
#pragma unroll
            for (int j = 0; j < 8; ++j) tf[j] = bf2f(tv[j]);
#pragma unroll
            for (int cy = 0; cy < 2; ++cy) {
                const int wy = dy - cy;
                if ((unsigned)wy >= 3u) continue;
#pragma unroll
                for (int cx = 0; cx < 2; ++cx) {
                    const int wx = dx - cx;
                    if ((unsigned)wx >= 3u) continue;
                    const float* wq = wf[wy * 3 + wx];
#pragma unroll
                    for (int j = 0; j < 8; ++j)
                        acc[cy][cx][j] = fmaf(wq[j], tf[j], acc[cy][cx][j]);
                }
            }
        }
    }
#pragma unroll
    for (int cy = 0; cy < 2; ++cy)
#pragma unroll
        for (int cx = 0; cx < 2; ++cx) {
            const int n = (cy == 0) ? (cx == 0 ? n00 : n01) : (cx == 0 ? n10 : n11);
            if (!n) continue;
            short8 o;
#pragma unroll
            for (int j = 0; j < 8; ++j) o[j] = f2bf(acc[cy][cx][j]);
            *(short8*)(convo + (size_t)(cell00 + cy * kW + cx) * kCHID + c0) = o;
        }
}

// ---------------------------------------------------------------------------
// map2token gather + fused skip: h2 = hb16*dws + num/(den+eps) -> hraw (bf16).
// 1 row per wave, unrolled x2. No stats atomics (R7/R16 lessons).
// ---------------------------------------------------------------------------
__global__ __launch_bounds__(256) void gather_tok_b(
    const short* __restrict__ convo, const int* __restrict__ off,
    const int* __restrict__ celllist, const float* __restrict__ wlist,
    const short* __restrict__ hb, const float* __restrict__ dws,
    short* __restrict__ h2)
{
    const int lane = threadIdx.x & 63;
    const int wave = threadIdx.x >> 6;
    const int t = blockIdx.x * 4 + wave;
    const int seg = kBHW + t;                      // token segments follow cells
    const int sbeg = off[seg - 1], send = off[seg];
    const int c0 = lane * 8;
    const short8 hv = *(const short8*)(hb + (size_t)t * kCHID + c0);
    const float4 d0 = *(const float4*)(dws + c0);
    const float4 d1 = *(const float4*)(dws + c0 + 4);
    const float dd[8] = {d0.x, d0.y, d0.z, d0.w, d1.x, d1.y, d1.z, d1.w};
    float a[8] = {};
    float den = 0.f;
    int j = sbeg;
    for (; j + 1 < send; j += 2) {
        const float w0 = wlist[j], w1 = wlist[j + 1];
        const int   cA = celllist[j], cBn = celllist[j + 1];
        den += w0 + w1;
        const short8 v0 = *(const short8*)(convo + (size_t)cA  * kCHID + c0);
        const short8 v1 = *(const short8*)(convo + (size_t)cBn * kCHID + c0);
#pragma unroll
        for (int k = 0; k < 8; ++k)
            a[k] += w0 * bf2f(v0[k]) + w1 * bf2f(v1[k]);
    }
    if (j < send) {
        const float w = wlist[j];
        den += w;
        const short8 v = *(const short8*)(convo + (size_t)celllist[j] * kCHID + c0);
#pragma unroll
        for (int k = 0; k < 8; ++k) a[k] = fmaf(w, bf2f(v[k]), a[k]);
    }
    const float r = 1.f / (den + kEPS);
    short8 o;
#pragma unroll
    for (int k = 0; k < 8; ++k)
        o[k] = f2bf(fmaf(bf2f(hv[k]), dd[k], a[k] * r));
    *(short8*)(h2 + (size_t)t * kCHID + c0) = o;
}

// ---------------------------------------------------------------------------
extern "C" void kernel_launch(void* const* d_in, const int* in_sizes, int n_in,
                              void* d_out, int out_size, void* d_ws, size_t ws_size,
                              hipStream_t stream)
{
    (void)in_sizes; (void)n_in; (void)out_size; (void)ws_size;
    const float* x    = (const float*)d_in[0];
    const float* loc  = (const float*)d_in[1];
    const int*   iagg = (const int*)  d_in[2];
    const float* aw   = (const float*)d_in[3];
    const float* fc1w = (const float*)d_in[4];
    const float* fc1b = (const float*)d_in[5];
    const float* g1   = (const float*)d_in[6];
    const float* b1   = (const float*)d_in[7];
    const float* dww  = (const float*)d_in[8];
    const float* dwb  = (const float*)d_in[9];
    const float* dwsw = (const float*)d_in[10];
    const float* g2   = (const float*)d_in[11];
    const float* b2   = (const float*)d_in[12];
    const float* fc2w = (const float*)d_in[13];
    const float* fc2b = (const float*)d_in[14];
    const float* g3   = (const float*)d_in[15];
    const float* b3   = (const float*)d_in[16];
    float* outp = (float*)d_out;

    float* ws = (float*)d_ws;
    // --- zeroed region: BN stats (2304 floats) + combined counts (62720 ints) ---
    float* gsum1 = ws + 0;
    float* gsq1  = ws + 512;
    float* gsum2 = ws + 1024;
    float* gsq2  = ws + 1536;
    float* gsum3 = ws + 2048;
    float* gsq3  = ws + 2176;
    int* cnt = (int*)(ws + 2304);                    // [kSEG]
    const size_t zero_bytes = (2304ull + kSEG) * 4;
    // --- non-zeroed (word offsets keep 16B alignment for short8 arrays) ---
    int*   off   = cnt + kSEG;                       // [kSEG] (+pad) -> 62724
    int*   bsum  = off + 62724;                      // [256]
    int*   ihw   = bsum + 256;                       // [kPTS]
    int*   slotA = ihw + kPTS;                       // [2*kPTS]
    float* w_all = (float*)(slotA + 2 * kPTS);       // [2*kPTS]
    short* wTb   = (short*)(w_all + 2 * kPTS);       // [4608]
    short* xt    = wTb + 4608;                       // [kROWS*kCIN] k-block
    short* w1t   = xt + (size_t)kROWS * kCIN;        // [512*128] k-block
    short* w2t   = w1t + 512 * 128;                  // [128*512] k-block
    short* hraw  = w2t + 128 * 512;                  // bf16 [kROWS][512] row-major
    short* hb16  = hraw + (size_t)kROWS * kCHID;     // bf16: BN1 row-major, then BN2 k-block
    short* smap  = hb16 + (size_t)kROWS * kCHID;     // bf16 [kBHW][512]
    short* convo = smap + (size_t)kBHW * kCHID;      // bf16 [kBHW][512]
    float* out3  = (float*)smap;                     // alias: smap dead after dwconv

    hipMemsetAsync(ws, 0, zero_bytes, stream);

    // prep: k-block transforms (x, w1, w2) + dw transpose + grid-index/counts
    prep_k<<<kXBlks + kW1Blks + kW2Blks + kWtBlks + kCntBlks, 256, 0, stream>>>(
        x, xt, fc1w, w1t, fc2w, w2t, dww, wTb, loc, iagg, ihw, cnt);

    // fc1 (k-block operands; MFMA -> bf16 row-major) + fused BN1 stats
    gemm_kb_k<1, 1><<<dim3(kROWS / 64, kCHID / 64), 256, 0, stream>>>(
        xt, w1t, fc1b, hraw, gsum1, gsq1, kROWS, kCHID, kCIN);

    // CSR scan (2 kernels) + fill
    scan1_k<<<kScanBlks, 256, 0, stream>>>(cnt, off, bsum);
    scan23_k<<<kScanBlks, 256, 0, stream>>>(off, bsum);
    fill_k<<<kPTS / 256, 256, 0, stream>>>(iagg, ihw, aw, off, slotA, w_all);

    // BN1 + GELU (row-major: feeds both gathers)
    bn_act_b<0><<<(kROWS * kCHID / 8) / 256, 256, 0, stream>>>(
        hraw, hb16, gsum1, gsq1, g1, b1, 1.f / kROWS);

    // token -> map (XCD-banded, zero-filled) -> dwconv (same banding: L2 handoff)
    gather_map_b<<<kGmBlks, 256, 0, stream>>>(hb16, off, slotA, smap);
    dwconv_b<<<kDwBlks, 256, 0, stream>>>(smap, cnt, wTb, dwb, convo);

    // map -> token (+fused skip), h2 -> hraw
    gather_tok_b<<<kROWS / 4, 256, 0, stream>>>(convo, off, slotA, w_all,
                                                hb16, dwsw, hraw);

    // BN2 stats + BN2+GELU -> k-block layout (fc2's A operand)
    colstats_b<<<196, 256, 0, stream>>>(hraw, gsum2, gsq2, 64);
    bn_act_b<1><<<(kROWS * kCHID / 8) / 256, 256, 0, stream>>>(
        hraw, hb16, gsum2, gsq2, g2, b2, 1.f / kROWS);

    // fc2 (k-block operands; MFMA -> fp32) + fused BN3 stats
    gemm_kb_k<0, 1><<<dim3(kROWS / 64, kCOUT / 64), 256, 0, stream>>>(
        hb16, w2t, fc2b, out3, gsum3, gsq3, kROWS, kCOUT, kCHID);

    // BN3 + GELU -> out (fp32)
    bn_act_f128<<<(kROWS * kCOUT / 4) / 256, 256, 0, stream>>>(
        out3, outp, gsum3, gsq3, g3, b3, 1.f / kROWS);
}

// Round 18
// 161.229 us; speedup vs baseline: 1.0851x; 1.0618x over previous
//
#include <hip/hip_runtime.h>
#include <math.h>

// Problem constants (fixed by the reference)
constexpr int kB    = 4;
constexpr int kN    = 3136;
constexpr int kN0   = 12544;
constexpr int kH    = 112, kW = 112;
constexpr int kHW   = kH * kW;          // 12544
constexpr int kCIN  = 128;
constexpr int kCHID = 512;
constexpr int kCOUT = 128;
constexpr int kROWS = kB * kN;          // 12544
constexpr int kPTS  = kB * kN0;         // 50176
constexpr int kBHW  = kB * kHW;         // 50176
constexpr int kSEG  = kBHW + kROWS;     // 62720 combined CSR segments
constexpr int kScanBlks = (kSEG + 255) / 256;   // 245
constexpr int kDwBlks   = kB * kHW / 16;        // 3136 (multiple of 8)
constexpr int kGmBlks   = kBHW / 4;             // 12544 (multiple of 8)
constexpr int kFc1Blks  = (kROWS / 64) * (kCHID / 64);   // 1568
constexpr int kBn1Blks  = (kROWS * kCHID / 8) / 256;     // 3136
constexpr float kEPS  = 1e-6f;
constexpr float kBEPS = 1e-5f;

typedef __attribute__((ext_vector_type(8))) short short8;
typedef __attribute__((ext_vector_type(4))) float f32x4;

__device__ __forceinline__ float gelu_f(float x) {
    return 0.5f * x * (1.0f + erff(x * 0.70710678118654752440f));
}
__device__ __forceinline__ float bf2f(short s) {
    union { unsigned u; float f; } v; v.u = ((unsigned)(unsigned short)s) << 16; return v.f;
}
__device__ __forceinline__ short f2bf(float f) {
    union { float f; unsigned u; } v; v.f = f;
    const unsigned r = v.u + 0x7fffu + ((v.u >> 16) & 1u);   // RNE
    return (short)(r >> 16);
}

// Build BN scale/shift for 512 channels into LDS (256 threads x 2 channels).
__device__ __forceinline__ void bn_coef_lds(
    const float* __restrict__ gsum, const float* __restrict__ gsq,
    const float* __restrict__ g, const float* __restrict__ bb,
    float invn, float* ssc, float* ssh)
{
    const int c = threadIdx.x * 2;
#pragma unroll
    for (int u = 0; u < 2; ++u) {
        const float m = gsum[c + u] * invn;
        const float v = fmaxf(gsq[c + u] * invn - m * m, 0.f);
        const float sc = g[c + u] * rsqrtf(v + kBEPS);
        ssc[c + u] = sc;
        ssh[c + u] = bb[c + u] - m * sc;
    }
}

// ---------------------------------------------------------------------------
// MFMA bf16 GEMM body, K-BLOCK operand layout: T[(k/8)*dim + idx][8].
// (R14 lesson: row-major fragment loads are address-divergent; k-block makes
//  16 lanes contiguous.) Fused per-column stats (<=392 writers/addr OK;
//  R7: never 3136 writers to the same 1024 addresses).
// ---------------------------------------------------------------------------
template <int OUT16, int STATS>
__device__ __forceinline__ void gemm_body(
    int bxm, int byn,
    const short* __restrict__ A, const short* __restrict__ W,
    const float* __restrict__ bias, void* __restrict__ Cv,
    float* __restrict__ gsum, float* __restrict__ gsq,
    int M, int N, int K, float* ls, float* lq)
{
    if (STATS) {
        if (threadIdx.x < 64) { ls[threadIdx.x] = 0.f; lq[threadIdx.x] = 0.f; }
        __syncthreads();
    }
    const int wave = threadIdx.x >> 6;
    const int lane = threadIdx.x & 63;
    const int r = lane & 15, kg = lane >> 4;
    const int bm = bxm * 64 + wave * 16;
    const int bn = byn * 64;
    f32x4 acc[4];
#pragma unroll
    for (int j = 0; j < 4; ++j) {
        const float bz = bias[bn + j * 16 + r];
        acc[j][0] = bz; acc[j][1] = bz; acc[j][2] = bz; acc[j][3] = bz;
    }
    for (int k0 = 0; k0 < K; k0 += 32) {
        const int kb = (k0 >> 3) + kg;
        const short8 av = *(const short8*)(A + ((size_t)kb * M + bm + r) * 8);
#pragma unroll
        for (int j = 0; j < 4; ++j) {
            const short8 bv = *(const short8*)(W + ((size_t)kb * N + bn + j * 16 + r) * 8);
            acc[j] = __builtin_amdgcn_mfma_f32_16x16x32_bf16(av, bv, acc[j], 0, 0, 0);
        }
    }
#pragma unroll
    for (int j = 0; j < 4; ++j)
#pragma unroll
        for (int q = 0; q < 4; ++q) {
            const size_t idx = (size_t)(bm + kg * 4 + q) * N + bn + j * 16 + r;
            if constexpr (OUT16) ((short*)Cv)[idx] = f2bf(acc[j][q]);
            else                 ((float*)Cv)[idx] = acc[j][q];
        }
    if (STATS) {
#pragma unroll
        for (int j = 0; j < 4; ++j) {
            const float s = acc[j][0] + acc[j][1] + acc[j][2] + acc[j][3];
            const float q = acc[j][0]*acc[j][0] + acc[j][1]*acc[j][1]
                          + acc[j][2]*acc[j][2] + acc[j][3]*acc[j][3];
            atomicAdd(&ls[j * 16 + r], s);
            atomicAdd(&lq[j * 16 + r], q);
        }
        __syncthreads();
        if (threadIdx.x < 64) {
            atomicAdd(&gsum[bn + threadIdx.x], ls[threadIdx.x]);
            atomicAdd(&gsq[bn + threadIdx.x],  lq[threadIdx.x]);
        }
    }
}

// scan1 body (per-block exclusive scan; bsum gets block total)
__device__ __forceinline__ void scan1_body(
    int sblk, const int* __restrict__ cnt, int* __restrict__ off,
    int* __restrict__ bsum, int* sh)
{
    const int t = threadIdx.x;
    const int i = sblk * 256 + t;
    const int v = (i < kSEG) ? cnt[i] : 0;
    sh[t] = v; __syncthreads();
#pragma unroll
    for (int o = 1; o < 256; o <<= 1) {
        const int tmp = (t >= o) ? sh[t - o] : 0;
        __syncthreads();
        sh[t] += tmp;
        __syncthreads();
    }
    if (i < kSEG) off[i] = sh[t] - v;
    if (t == 255) bsum[sblk] = sh[255];
}

// ---------------------------------------------------------------------------
// FUSED launch: fc1 GEMM (1568 blocks, flattened m=blk>>3, n=blk&7) + scan1
// (245 blocks). Both depend only on prep -> safe to co-launch.
// ---------------------------------------------------------------------------
__global__ __launch_bounds__(256) void fc1_scan1_k(
    const short* __restrict__ xt, const short* __restrict__ w1t,
    const float* __restrict__ fc1b, short* __restrict__ hraw,
    float* __restrict__ gsum1, float* __restrict__ gsq1,
    const int* __restrict__ cnt, int* __restrict__ off, int* __restrict__ bsum)
{
    __shared__ int shI[256];
    __shared__ float ls[64], lq[64];
    if (blockIdx.x < kFc1Blks) {
        gemm_body<1, 1>(blockIdx.x >> 3, blockIdx.x & 7, xt, w1t, fc1b, hraw,
                        gsum1, gsq1, kROWS, kCHID, kCIN, ls, lq);
    } else {
        scan1_body(blockIdx.x - kFc1Blks, cnt, off, bsum, shI);
    }
}

// fc2 GEMM (standalone)
template <int OUT16, int STATS>
__global__ __launch_bounds__(256) void gemm_kb_k(
    const short* __restrict__ A, const short* __restrict__ W,
    const float* __restrict__ bias, void* __restrict__ Cv,
    float* __restrict__ gsum, float* __restrict__ gsq,
    int M, int N, int K)
{
    __shared__ float ls[64], lq[64];
    gemm_body<OUT16, STATS>(blockIdx.x, blockIdx.y, A, W, bias, Cv,
                            gsum, gsq, M, N, K, ls, lq);
}

// ---------------------------------------------------------------------------
// prep: k-block transforms of x, fc1_w, fc2_w (fp32 -> bf16), dw-weight
// transpose, grid-index + combined counts. Partitioned by blockIdx range.
// ---------------------------------------------------------------------------
constexpr int kXBlks  = kROWS * (kCIN / 8) / 256;        // 784
constexpr int kW1Blks = kCHID * (kCIN / 8) / 256;        // 32
constexpr int kW2Blks = kCOUT * (kCHID / 8) / 256;       // 32
constexpr int kWtBlks = (9 * 512 + 255) / 256;           // 18
constexpr int kCntBlks = kPTS / 256;                     // 196

__device__ __forceinline__ void cvt8_to(const float* __restrict__ in, short* __restrict__ out) {
    const float4 v0 = ((const float4*)in)[0];
    const float4 v1 = ((const float4*)in)[1];
    short8 o;
    o[0] = f2bf(v0.x); o[1] = f2bf(v0.y); o[2] = f2bf(v0.z); o[3] = f2bf(v0.w);
    o[4] = f2bf(v1.x); o[5] = f2bf(v1.y); o[6] = f2bf(v1.z); o[7] = f2bf(v1.w);
    *(short8*)out = o;
}

__global__ void prep_k(const float* __restrict__ x, short* __restrict__ xt,
                       const float* __restrict__ w1, short* __restrict__ w1t,
                       const float* __restrict__ w2, short* __restrict__ w2t,
                       const float* __restrict__ dww, short* __restrict__ wTb,
                       const float* __restrict__ loc, const int* __restrict__ iagg,
                       int* __restrict__ ihw, int* __restrict__ cnt)
{
    int blk = blockIdx.x;
    if (blk < kXBlks) {                       // x: [12544][128] -> k-block
        const int i = blk * 256 + threadIdx.x;
        const int m = i >> 4, kb = i & 15;
        cvt8_to(x + (size_t)m * kCIN + kb * 8, xt + ((size_t)kb * kROWS + m) * 8);
        return;
    }
    blk -= kXBlks;
    if (blk < kW1Blks) {                      // w1: [512][128] -> k-block
        const int i = blk * 256 + threadIdx.x;
        const int n = i >> 4, kb = i & 15;
        cvt8_to(w1 + (size_t)n * kCIN + kb * 8, w1t + ((size_t)kb * kCHID + n) * 8);
        return;
    }
    blk -= kW1Blks;
    if (blk < kW2Blks) {                      // w2: [128][512] -> k-block
        const int i = blk * 256 + threadIdx.x;
        const int n = i >> 6, kb = i & 63;
        cvt8_to(w2 + (size_t)n * kCHID + kb * 8, w2t + ((size_t)kb * kCOUT + n) * 8);
        return;
    }
    blk -= kW2Blks;
    if (blk < kWtBlks) {                      // dw weights: [512][9] -> [9][512]
        const int j = blk * 256 + threadIdx.x;
        if (j < 9 * 512) {
            const int tap = j / 512, ch = j % 512;
            wTb[j] = f2bf(dww[ch * 9 + tap]);
        }
        return;
    }
    blk -= kWtBlks;
    const int p = blk * 256 + threadIdx.x;    // grid-index + counts
    if (p >= kPTS) return;
    float lx = loc[(size_t)p * 2 + 0];
    float ly = loc[(size_t)p * 2 + 1];
    lx = fminf(fmaxf(lx, -1.f), 1.f) * 0.5f + 0.5f;
    ly = fminf(fmaxf(ly, -1.f), 1.f) * 0.5f + 0.5f;
    int gx = (int)rintf(lx * (float)(kW - 1)); gx = min(max(gx, 0), kW - 1);
    int gy = (int)rintf(ly * (float)(kH - 1)); gy = min(max(gy, 0), kH - 1);
    const int idx = gy * kW + gx;
    ihw[p] = idx;
    const int b = p / kN0;
    atomicAdd(cnt + b * kHW + idx, 1);
    atomicAdd(cnt + kBHW + b * kN + iagg[p], 1);
}

// ---------------------------------------------------------------------------
// scan23: each block redundantly scans bsum in LDS -> adds its prefix.
// ---------------------------------------------------------------------------
__global__ __launch_bounds__(256) void scan23_k(int* __restrict__ off,
                                                const int* __restrict__ bsum)
{
    __shared__ int sh[256];
    const int t = threadIdx.x;
    const int v = (t < kScanBlks) ? bsum[t] : 0;
    sh[t] = v; __syncthreads();
#pragma unroll
    for (int o = 1; o < 256; o <<= 1) {
        const int tmp = (t >= o) ? sh[t - o] : 0;
        __syncthreads();
        sh[t] += tmp;
        __syncthreads();
    }
    const int add = sh[blockIdx.x] - bsum[blockIdx.x];
    const int i = blockIdx.x * 256 + t;
    if (i < kSEG) off[i] += add;
}

// ---------------------------------------------------------------------------
// FUSED launch: fill (196 blocks; dep scan23) + BN1+GELU row-major (3136
// blocks; dep fc1). Both deps satisfied at this point in the DAG.
// After fill, off[i] = segment END; segment i = [off[i-1], off[i]).
// ---------------------------------------------------------------------------
__global__ __launch_bounds__(256) void fill_bn1_k(
    const int* __restrict__ iagg, const int* __restrict__ ihw,
    const float* __restrict__ aw, int* __restrict__ off,
    int* __restrict__ slotA, float* __restrict__ w_all,
    const short* __restrict__ hraw, short* __restrict__ hb16,
    const float* __restrict__ gsum, const float* __restrict__ gsq,
    const float* __restrict__ g, const float* __restrict__ bb)
{
    if (blockIdx.x < kCntBlks) {
        const int p = blockIdx.x * 256 + threadIdx.x;
        if (p >= kPTS) return;
        const int b = p / kN0;
        const int tokrow = b * kN + iagg[p];
        const int cell   = b * kHW + ihw[p];
        const int cpos = atomicAdd(off + cell, 1);
        slotA[cpos] = tokrow;
        const int tpos = atomicAdd(off + kBHW + tokrow, 1);
        slotA[tpos] = cell;
        w_all[tpos] = aw[p];
    } else {
        __shared__ float ssc[512], ssh[512];
        bn_coef_lds(gsum, gsq, g, bb, 1.f / kROWS, ssc, ssh);
        __syncthreads();
        const size_t i = (size_t)(blockIdx.x - kCntBlks) * 256 + threadIdx.x;
        const int c0 = (int)(i & 63) * 8;
        const short8 v = *(const short8*)(hraw + i * 8);
        short8 o;
#pragma unroll
        for (int j = 0; j < 8; ++j)
            o[j] = f2bf(gelu_f(fmaf(bf2f(v[j]), ssc[c0 + j], ssh[c0 + j])));
        *(short8*)(hb16 + i * 8) = o;
    }
}

// ---------------------------------------------------------------------------
// Column stats over bf16 [rows][512] (196 blocks -> low atomic contention).
// ---------------------------------------------------------------------------
__global__ __launch_bounds__(256) void colstats_b(
    const short* __restrict__ X, float* __restrict__ gsum, float* __restrict__ gsq,
    int rows_per_blk)
{
    __shared__ float shs[4][512];
    __shared__ float shq[4][512];
    const int g = threadIdx.x & 63;
    const int rr = threadIdx.x >> 6;
    const int r0 = blockIdx.x * rows_per_blk;
    float s[8] = {}, q[8] = {};
    for (int r = rr; r < rows_per_blk; r += 4) {
        const short8 v = *(const short8*)(X + (size_t)(r0 + r) * kCHID + g * 8);
#pragma unroll
        for (int j = 0; j < 8; ++j) { const float f = bf2f(v[j]); s[j] += f; q[j] += f * f; }
    }
#pragma unroll
    for (int j = 0; j < 8; ++j) { shs[rr][g * 8 + j] = s[j]; shq[rr][g * 8 + j] = q[j]; }
    __syncthreads();
    const int c = threadIdx.x * 2;
    const float s0 = shs[0][c] + shs[1][c] + shs[2][c] + shs[3][c];
    const float s1 = shs[0][c+1] + shs[1][c+1] + shs[2][c+1] + shs[3][c+1];
    const float q0 = shq[0][c] + shq[1][c] + shq[2][c] + shq[3][c];
    const float q1 = shq[0][c+1] + shq[1][c+1] + shq[2][c+1] + shq[3][c+1];
    atomicAdd(&gsum[c], s0);   atomicAdd(&gsum[c+1], s1);
    atomicAdd(&gsq[c],  q0);   atomicAdd(&gsq[c+1],  q1);
}

// ---------------------------------------------------------------------------
// BN (inline coef) + GELU -> K-BLOCK layout (fc2's A operand).
// ---------------------------------------------------------------------------
__global__ __launch_bounds__(256) void bn_act_kb(
    const short* __restrict__ in, short* __restrict__ out,
    const float* __restrict__ gsum, const float* __restrict__ gsq,
    const float* __restrict__ g, const float* __restrict__ bb, float invn)
{
    __shared__ float ssc[512], ssh[512];
    bn_coef_lds(gsum, gsq, g, bb, invn, ssc, ssh);
    __syncthreads();
    const size_t i = (size_t)blockIdx.x * 256 + threadIdx.x;   // over rows*512/8
    const int cg = (int)(i & 63);
    const int c0 = cg * 8;
    const size_t row = i >> 6;
    const short8 v = *(const short8*)(in + i * 8);
    short8 o;
#pragma unroll
    for (int j = 0; j < 8; ++j)
        o[j] = f2bf(gelu_f(fmaf(bf2f(v[j]), ssc[c0 + j], ssh[c0 + j])));
    *(short8*)(out + ((size_t)cg * kROWS + row) * 8) = o;
}

__global__ __launch_bounds__(256) void bn_act_f128(
    const float* __restrict__ in, float* __restrict__ out,
    const float* __restrict__ gsum, const float* __restrict__ gsq,
    const float* __restrict__ g, const float* __restrict__ bb, float invn)
{
    __shared__ float ssc[128], ssh[128];
    if (threadIdx.x < 128) {
        const int c = threadIdx.x;
        const float m = gsum[c] * invn;
        const float v = fmaxf(gsq[c] * invn - m * m, 0.f);
        const float sc = g[c] * rsqrtf(v + kBEPS);
        ssc[c] = sc;
        ssh[c] = bb[c] - m * sc;
    }
    __syncthreads();
    const size_t i = (size_t)blockIdx.x * 256 + threadIdx.x;   // over rows*128/4
    const int c0 = (int)(i & 31) * 4;
    float4 v = ((const float4*)in)[i];
    v.x = gelu_f(fmaf(v.x, ssc[c0 + 0], ssh[c0 + 0]));
    v.y = gelu_f(fmaf(v.y, ssc[c0 + 1], ssh[c0 + 1]));
    v.z = gelu_f(fmaf(v.z, ssc[c0 + 2], ssh[c0 + 2]));
    v.w = gelu_f(fmaf(v.w, ssc[c0 + 3], ssh[c0 + 3]));
    ((float4*)out)[i] = v;
}

// ---------------------------------------------------------------------------
// token2map gather (bf16, post-BN1): one wave per cell, 8 ch/lane. Empty -> 0.
// XCD-banded (same mapping as dwconv): smap handoff stays in per-XCD L2.
// ---------------------------------------------------------------------------
__global__ __launch_bounds__(256) void gather_map_b(
    const short* __restrict__ hb, const int* __restrict__ off,
    const int* __restrict__ toklist, short* __restrict__ smap)
{
    constexpr int kChunkG = kGmBlks / 8;        // 1568
    const int wg = (blockIdx.x & 7) * kChunkG + (blockIdx.x >> 3);
    const int lane = threadIdx.x & 63;
    const int cell = wg * 4 + (threadIdx.x >> 6);
    const int s = cell ? off[cell - 1] : 0;
    const int e = off[cell];
    const int c0 = lane * 8;
    float a[8] = {};
    int j = s;
    for (; j + 1 < e; j += 2) {
        const int t0 = toklist[j], t1 = toklist[j + 1];
        const short8 v0 = *(const short8*)(hb + (size_t)t0 * kCHID + c0);
        const short8 v1 = *(const short8*)(hb + (size_t)t1 * kCHID + c0);
#pragma unroll
        for (int t = 0; t < 8; ++t) a[t] += bf2f(v0[t]) + bf2f(v1[t]);
    }
    if (j < e) {
        const short8 v = *(const short8*)(hb + (size_t)toklist[j] * kCHID + c0);
#pragma unroll
        for (int t = 0; t < 8; ++t) a[t] += bf2f(v[t]);
    }
    const float sc = 1.f / ((float)(e - s) + kEPS);
    short8 o;
#pragma unroll
    for (int t = 0; t < 8; ++t) o[t] = f2bf(a[t] * sc);
    *(short8*)(smap + (size_t)cell * kCHID + c0) = o;
}

// ---------------------------------------------------------------------------
// Depthwise 3x3 bf16, zero-filled map. 2x2 cells x 8 ch per thread.
// XCD-chunked blockIdx swizzle (T1).
// ---------------------------------------------------------------------------
__global__ __launch_bounds__(256) void dwconv_b(
    const short* __restrict__ smap, const int* __restrict__ cnt,
    const short* __restrict__ wTb, const float* __restrict__ bdw,
    short* __restrict__ convo)
{
    constexpr int kTX = kW / 2;                 // 56
    constexpr int kChunk = kDwBlks / 8;         // 392
    const int wg = (blockIdx.x & 7) * kChunk + (blockIdx.x >> 3);
    const int c8 = threadIdx.x & 63;
    const int w  = wg * 4 + (threadIdx.x >> 6);
    const int b   = w / (kTX * kTX);
    const int rem = w % (kTX * kTX);
    const int ty = rem / kTX, tx = rem % kTX;
    const int y0 = ty * 2, x0 = tx * 2;
    const int gbase = b * kHW;
    const int c0 = c8 * 8;

    const int cell00 = gbase + y0 * kW + x0;    // even -> int2 aligned
    const int2 nA = *(const int2*)(cnt + cell00);
    const int2 nB = *(const int2*)(cnt + cell00 + kW);
    const int n00 = nA.x, n01 = nA.y, n10 = nB.x, n11 = nB.y;
    if ((n00 | n01 | n10 | n11) == 0) return;

    float wf[9][8];
#pragma unroll
    for (int t = 0; t < 9; ++t) {
        const short8 wv = *(const short8*)(wTb + t * kCHID + c0);
#pragma unroll
        for (int j = 0; j < 8; ++j) wf[t][j] = bf2f(wv[j]);
    }
    float bz[8];
    {
        const float4 b0 = *(const float4*)(bdw + c0);
        const float4 b1 = *(const float4*)(bdw + c0 + 4);
        bz[0] = b0.x; bz[1] = b0.y; bz[2] = b0.z; bz[3] = b0.w;
        bz[4] = b1.x; bz[5] = b1.y; bz[6] = b1.z; bz[7] = b1.w;
    }
    float acc[2][2][8];
#pragma unroll
    for (int cy = 0; cy < 2; ++cy)
#pragma unroll
        for (int cx = 0; cx < 2; ++cx)
#pragma unroll
            for (int j = 0; j < 8; ++j) acc[cy][cx][j] = bz[j];

#pragma unroll
    for (int dy = 0; dy < 4; ++dy) {
        const int yy = y0 - 1 + dy;
        if ((unsigned)yy >= (unsigned)kH) continue;
#pragma unroll
        for (int dx = 0; dx < 4; ++dx) {
            const int xx = x0 - 1 + dx;
            if ((unsigned)xx >= (unsigned)kW) continue;
            const short8 tv = *(const short8*)(smap + (size_t)(gbase + yy * kW + xx) * kCHID + c0);
            float tf[8];
#pragma unroll
            for (int j = 0; j < 8; ++j) tf[j] = bf2f(tv[j]);
#pragma unroll
            for (int cy = 0; cy < 2; ++cy) {
                const int wy = dy - cy;
                if ((unsigned)wy >= 3u) continue;
#pragma unroll
                for (int cx = 0; cx < 2; ++cx) {
                    const int wx = dx - cx;
                    if ((unsigned)wx >= 3u) continue;
                    const float* wq = wf[wy * 3 + wx];
#pragma unroll
                    for (int j = 0; j < 8; ++j)
                        acc[cy][cx][j] = fmaf(wq[j], tf[j], acc[cy][cx][j]);
                }
            }
        }
    }
#pragma unroll
    for (int cy = 0; cy < 2; ++cy)
#pragma unroll
        for (int cx = 0; cx < 2; ++cx) {
            const int n = (cy == 0) ? (cx == 0 ? n00 : n01) : (cx == 0 ? n10 : n11);
            if (!n) continue;
            short8 o;
#pragma unroll
            for (int j = 0; j < 8; ++j) o[j] = f2bf(acc[cy][cx][j]);
            *(short8*)(convo + (size_t)(cell00 + cy * kW + cx) * kCHID + c0) = o;
        }
}

// ---------------------------------------------------------------------------
// map2token gather + fused skip: h2 = hb16*dws + num/(den+eps) -> hraw (bf16).
// 1 row per wave, unrolled x2. No stats atomics (R7/R16 lessons).
// ---------------------------------------------------------------------------
__global__ __launch_bounds__(256) void gather_tok_b(
    const short* __restrict__ convo, const int* __restrict__ off,
    const int* __restrict__ celllist, const float* __restrict__ wlist,
    const short* __restrict__ hb, const float* __restrict__ dws,
    short* __restrict__ h2)
{
    const int lane = threadIdx.x & 63;
    const int wave = threadIdx.x >> 6;
    const int t = blockIdx.x * 4 + wave;
    const int seg = kBHW + t;                      // token segments follow cells
    const int sbeg = off[seg - 1], send = off[seg];
    const int c0 = lane * 8;
    const short8 hv = *(const short8*)(hb + (size_t)t * kCHID + c0);
    const float4 d0 = *(const float4*)(dws + c0);
    const float4 d1 = *(const float4*)(dws + c0 + 4);
    const float dd[8] = {d0.x, d0.y, d0.z, d0.w, d1.x, d1.y, d1.z, d1.w};
    float a[8] = {};
    float den = 0.f;
    int j = sbeg;
    for (; j + 1 < send; j += 2) {
        const float w0 = wlist[j], w1 = wlist[j + 1];
        const int   cA = celllist[j], cBn = celllist[j + 1];
        den += w0 + w1;
        const short8 v0 = *(const short8*)(convo + (size_t)cA  * kCHID + c0);
        const short8 v1 = *(const short8*)(convo + (size_t)cBn * kCHID + c0);
#pragma unroll
        for (int k = 0; k < 8; ++k)
            a[k] += w0 * bf2f(v0[k]) + w1 * bf2f(v1[k]);
    }
    if (j < send) {
        const float w = wlist[j];
        den += w;
        const short8 v = *(const short8*)(convo + (size_t)celllist[j] * kCHID + c0);
#pragma unroll
        for (int k = 0; k < 8; ++k) a[k] = fmaf(w, bf2f(v[k]), a[k]);
    }
    const float r = 1.f / (den + kEPS);
    short8 o;
#pragma unroll
    for (int k = 0; k < 8; ++k)
        o[k] = f2bf(fmaf(bf2f(hv[k]), dd[k], a[k] * r));
    *(short8*)(h2 + (size_t)t * kCHID + c0) = o;
}

// ---------------------------------------------------------------------------
extern "C" void kernel_launch(void* const* d_in, const int* in_sizes, int n_in,
                              void* d_out, int out_size, void* d_ws, size_t ws_size,
                              hipStream_t stream)
{
    (void)in_sizes; (void)n_in; (void)out_size; (void)ws_size;
    const float* x    = (const float*)d_in[0];
    const float* loc  = (const float*)d_in[1];
    const int*   iagg = (const int*)  d_in[2];
    const float* aw   = (const float*)d_in[3];
    const float* fc1w = (const float*)d_in[4];
    const float* fc1b = (const float*)d_in[5];
    const float* g1   = (const float*)d_in[6];
    const float* b1   = (const float*)d_in[7];
    const float* dww  = (const float*)d_in[8];
    const float* dwb  = (const float*)d_in[9];
    const float* dwsw = (const float*)d_in[10];
    const float* g2   = (const float*)d_in[11];
    const float* b2   = (const float*)d_in[12];
    const float* fc2w = (const float*)d_in[13];
    const float* fc2b = (const float*)d_in[14];
    const float* g3   = (const float*)d_in[15];
    const float* b3   = (const float*)d_in[16];
    float* outp = (float*)d_out;

    float* ws = (float*)d_ws;
    // --- zeroed region: BN stats (2304 floats) + combined counts (62720 ints) ---
    float* gsum1 = ws + 0;
    float* gsq1  = ws + 512;
    float* gsum2 = ws + 1024;
    float* gsq2  = ws + 1536;
    float* gsum3 = ws + 2048;
    float* gsq3  = ws + 2176;
    int* cnt = (int*)(ws + 2304);                    // [kSEG]
    const size_t zero_bytes = (2304ull + kSEG) * 4;
    // --- non-zeroed (word offsets keep 16B alignment for short8 arrays) ---
    int*   off   = cnt + kSEG;                       // [kSEG] (+pad) -> 62724
    int*   bsum  = off + 62724;                      // [256]
    int*   ihw   = bsum + 256;                       // [kPTS]
    int*   slotA = ihw + kPTS;                       // [2*kPTS]
    float* w_all = (float*)(slotA + 2 * kPTS);       // [2*kPTS]
    short* wTb   = (short*)(w_all + 2 * kPTS);       // [4608]
    short* xt    = wTb + 4608;                       // [kROWS*kCIN] k-block
    short* w1t   = xt + (size_t)kROWS * kCIN;        // [512*128] k-block
    short* w2t   = w1t + 512 * 128;                  // [128*512] k-block
    short* hraw  = w2t + 128 * 512;                  // bf16 [kROWS][512] row-major
    short* hb16  = hraw + (size_t)kROWS * kCHID;     // bf16: BN1 row-major, then BN2 k-block
    short* smap  = hb16 + (size_t)kROWS * kCHID;     // bf16 [kBHW][512]
    short* convo = smap + (size_t)kBHW * kCHID;      // bf16 [kBHW][512]
    float* out3  = (float*)smap;                     // alias: smap dead after dwconv

    hipMemsetAsync(ws, 0, zero_bytes, stream);

    // prep: k-block transforms (x, w1, w2) + dw transpose + grid-index/counts
    prep_k<<<kXBlks + kW1Blks + kW2Blks + kWtBlks + kCntBlks, 256, 0, stream>>>(
        x, xt, fc1w, w1t, fc2w, w2t, dww, wTb, loc, iagg, ihw, cnt);

    // FUSED: fc1 GEMM (+BN1 stats) || scan1 — both depend only on prep
    fc1_scan1_k<<<kFc1Blks + kScanBlks, 256, 0, stream>>>(
        xt, w1t, fc1b, hraw, gsum1, gsq1, cnt, off, bsum);

    // scan23 (dep scan1)
    scan23_k<<<kScanBlks, 256, 0, stream>>>(off, bsum);

    // FUSED: fill (dep scan23) || BN1+GELU (dep fc1)
    fill_bn1_k<<<kCntBlks + kBn1Blks, 256, 0, stream>>>(
        iagg, ihw, aw, off, slotA, w_all, hraw, hb16, gsum1, gsq1, g1, b1);

    // token -> map (XCD-banded, zero-filled) -> dwconv (same banding: L2 handoff)
    gather_map_b<<<kGmBlks, 256, 0, stream>>>(hb16, off, slotA, smap);
    dwconv_b<<<kDwBlks, 256, 0, stream>>>(smap, cnt, wTb, dwb, convo);

    // map -> token (+fused skip), h2 -> hraw
    gather_tok_b<<<kROWS / 4, 256, 0, stream>>>(convo, off, slotA, w_all,
                                                hb16, dwsw, hraw);

    // BN2 stats + BN2+GELU -> k-block layout (fc2's A operand)
    colstats_b<<<196, 256, 0, stream>>>(hraw, gsum2, gsq2, 64);
    bn_act_kb<<<kBn1Blks, 256, 0, stream>>>(
        hraw, hb16, gsum2, gsq2, g2, b2, 1.f / kROWS);

    // fc2 (k-block operands; MFMA -> fp32) + fused BN3 stats
    gemm_kb_k<0, 1><<<dim3(kROWS / 64, kCOUT / 64), 256, 0, stream>>>(
        hb16, w2t, fc2b, out3, gsum3, gsq3, kROWS, kCOUT, kCHID);

    // BN3 + GELU -> out (fp32)
    bn_act_f128<<<(kROWS * kCOUT / 4) / 256, 256, 0, stream>>>(
        out3, outp, gsum3, gsq3, g3, b3, 1.f / kROWS);
}